// Round 18
// baseline (324.518 us; speedup 1.0000x reference)
//
#include <hip/hip_runtime.h>
#include <math.h>

#define TS 45            // LDS tile stride (32 rows x 44 used cols, +1 pad)
#define FINF 3.4e38f
#define NPIX (384 * 384)

__device__ __forceinline__ int iclip(int v, int hi) {
  return v < 0 ? 0 : (v > hi ? hi : v);
}

// Exact f32 values of the reference D8 (computed in f64, cast to f32).
constexpr float CA = 0.35355339059327373f;
constexpr float K1 = 0.49039264020161522f;
constexpr float K2 = 0.46193976625564337f;
constexpr float K3 = 0.41573480615127262f;
constexpr float K4 = 0.35355339059327379f;
constexpr float K5 = 0.27778511650980111f;
constexpr float K6 = 0.19134171618254489f;
constexpr float K7 = 0.097545161008064135f;

constexpr float DCT8[8][8] = {
  { CA, CA, CA, CA, CA, CA, CA, CA},
  { K1, K3, K5, K7,-K7,-K5,-K3,-K1},
  { K2, K6,-K6,-K2,-K2,-K6, K6, K2},
  { K3,-K7,-K1,-K5, K5, K1, K7,-K3},
  { K4,-K4,-K4, K4, K4,-K4,-K4, K4},
  { K5,-K1, K7, K3,-K3,-K7, K1,-K5},
  { K6,-K2, K2,-K6,-K6, K2,-K2, K6},
  { K7,-K5, K3,-K1, K1,-K3, K5,-K7},
};

// lane-xor exchange: DPP for 1/2/8, ds_swizzle for 4/16, shfl for 32
__device__ __forceinline__ int sxor_i(int v, int m) {
  switch (m) {
    case 1:  return __builtin_amdgcn_update_dpp(0, v, 0xB1, 0xF, 0xF, true);
    case 2:  return __builtin_amdgcn_update_dpp(0, v, 0x4E, 0xF, 0xF, true);
    case 4:  return __builtin_amdgcn_ds_swizzle(v, (4 << 10) | 0x1F);
    case 8:  return __builtin_amdgcn_update_dpp(0, v, 0x128, 0xF, 0xF, true); // row_ror:8 == xor 8 (proven R9/R10)
    case 16: return __builtin_amdgcn_ds_swizzle(v, (16 << 10) | 0x1F);
    default: return __shfl_xor(v, 32, 64);
  }
}
__device__ __forceinline__ float sxor_f(float v, int m) {
  return __int_as_float(sxor_i(__float_as_int(v), m));
}

// broadcast from lane ((lane & ~7) | b) — 8-lane-group broadcast via ds_swizzle
// BitMode: offset = (xor<<10) | (or<<5) | and ; addr = ((lane&and)|or)^xor
__device__ __forceinline__ float bcast8(float v, int b) {
  int x = __float_as_int(v), r;
  switch (b) {
    case 0: r = __builtin_amdgcn_ds_swizzle(x, (0 << 5) | 0x18); break;
    case 1: r = __builtin_amdgcn_ds_swizzle(x, (1 << 5) | 0x18); break;
    case 2: r = __builtin_amdgcn_ds_swizzle(x, (2 << 5) | 0x18); break;
    case 3: r = __builtin_amdgcn_ds_swizzle(x, (3 << 5) | 0x18); break;
    case 4: r = __builtin_amdgcn_ds_swizzle(x, (4 << 5) | 0x18); break;
    case 5: r = __builtin_amdgcn_ds_swizzle(x, (5 << 5) | 0x18); break;
    case 6: r = __builtin_amdgcn_ds_swizzle(x, (6 << 5) | 0x18); break;
    default: r = __builtin_amdgcn_ds_swizzle(x, (7 << 5) | 0x18); break;
  }
  return __int_as_float(r);
}

// forward 2D DCT for one patch row per lane: row pass (lane-local literals),
// column pass (8-lane-group mix; Ca[b] = D8[r8][b])
__device__ __forceinline__ void fwd8(float X[8], const float Ca[8]) {
  float U[8];
#pragma unroll
  for (int d = 0; d < 8; d++) {
    float s = X[0] * DCT8[d][0];
#pragma unroll
    for (int c = 1; c < 8; c++) s += X[c] * DCT8[d][c];
    U[d] = s;
  }
#pragma unroll
  for (int d = 0; d < 8; d++) X[d] = 0.f;
#pragma unroll
  for (int b = 0; b < 8; b++)
#pragma unroll
    for (int d = 0; d < 8; d++) X[d] += Ca[b] * bcast8(U[d], b);
}

// inverse 2D DCT: column pass (Ct[a] = D8[a][r8]) then row pass (literals)
__device__ __forceinline__ void inv8(float X[8], const float Ct[8]) {
  float U[8];
#pragma unroll
  for (int d = 0; d < 8; d++) U[d] = 0.f;
#pragma unroll
  for (int a = 0; a < 8; a++)
#pragma unroll
    for (int d = 0; d < 8; d++) U[d] += Ct[a] * bcast8(X[d], a);
#pragma unroll
  for (int c = 0; c < 8; c++) {
    float s = U[0] * DCT8[0][c];
#pragma unroll
    for (int d = 1; d < 8; d++) s += U[d] * DCT8[d][c];
    X[c] = s;
  }
}

// 16-point WHT over k = (gwave<<3)|(lane>>3): k bits 0-2 in-wave (masks
// 8/16/32, ascending = same stage order as before), k bit 3 cross-wave via
// LDS float4 chunks. Scale 1/4.
__device__ __forceinline__ void had16x(float X[8], int lane, int gwave,
                                       float4* xs, const float4* xp) {
#pragma unroll
  for (int m = 8; m <= 32; m <<= 1) {
    bool hi = (lane & m) != 0;
#pragma unroll
    for (int d = 0; d < 8; d++) {
      float tv = sxor_f(X[d], m);
      X[d] = hi ? (tv - X[d]) : (X[d] + tv);
    }
  }
  bool hi = gwave != 0;
#pragma unroll
  for (int d0 = 0; d0 < 8; d0 += 4) {
    *xs = make_float4(X[d0], X[d0 + 1], X[d0 + 2], X[d0 + 3]);
    __syncthreads();
    float4 tv = *xp;
    X[d0]     = hi ? (tv.x - X[d0])     : (X[d0] + tv.x);
    X[d0 + 1] = hi ? (tv.y - X[d0 + 1]) : (X[d0 + 1] + tv.y);
    X[d0 + 2] = hi ? (tv.z - X[d0 + 2]) : (X[d0 + 2] + tv.z);
    X[d0 + 3] = hi ? (tv.w - X[d0 + 3]) : (X[d0 + 3] + tv.w);
    __syncthreads();
  }
#pragma unroll
  for (int d = 0; d < 8; d++) X[d] *= 0.25f;
}

// WIEN=0: match source = img. WIEN=1: match source = num1/den1 (basic).
// 512 threads = 8 waves = 4 groups x 2 waves; lane owns ONE patch row.
// NOTE: 2nd launch_bounds arg behaves as CUDA blocks-per-CU on this hipcc:
// VGPR budget = 2048 / (arg * waves_per_block). (512,2) -> 128 VGPR, no spill.
template <int WIEN>
__global__ __launch_bounds__(512, 2) void bm3d_pass(
    const int* __restrict__ img,
    const float* __restrict__ bn, const float* __restrict__ bd,
    const int* __restrict__ pvar,
    float* __restrict__ num, float* __restrict__ den) {
  __shared__ float ldsD[64];
  __shared__ int   wsel[4][16];
  __shared__ __align__(16) float wdistP[8][84];
  __shared__ float4 xbuf[8][64];
  __shared__ float pbuf[8];
  __shared__ float tileN[32 * TS];
  __shared__ float tileB[WIEN ? 32 * TS : 1];
  __shared__ float accN[32 * TS], accD[32 * TS];

  int t = threadIdx.x;
  int brow = blockIdx.x / 24, bcb = blockIdx.x - brow * 24;
  int ri = brow * 4;
  int bim = ri - 12;       int bi = bim < 0 ? 0 : (bim > 352 ? 352 : bim);
  int ubm = 16 * bcb - 12; int ub = ubm < 0 ? 0 : (ubm > 352 ? 352 : ubm);

  if (t < 64) ldsD[t] = DCT8[t >> 3][t & 7];
  for (int e = t; e < 32 * 44; e += 512) {
    int r = e / 44, c = e - r * 44;
    int col = ub + c;
    bool ok = col < 384;
    int gidx = (bi + r) * 384 + col;
    tileN[r * TS + c] = ok ? (float)img[gidx] : 0.f;
    if (WIEN)
      tileB[r * TS + c] = ok ? (bn[gidx] / fmaxf(bd[gidx], 1e-8f)) : 0.f;
  }
  for (int e = t; e < 32 * TS; e += 512) { accN[e] = 0.f; accD[e] = 0.f; }
  __syncthreads();

  float sigma2 = (float)pvar[0];
  int wv = t >> 6, lane = t & 63;
  int gl = wv >> 1, gwave = wv & 1;
  int gc = bcb * 4 + gl;
  bool active = gc < 95;
  int rj = (active ? gc : 94) * 4;
  const float* tileS = WIEN ? tileB : tileN;

  // ---------- block match: each wave computes 4-row PARTIALS ----------
  int cB = lane < 17 ? 64 + lane : 80;
  int aiA = iclip(ri + (lane / 9) * 3 - 12, 376) - bi;
  int ajA = iclip(rj + (lane % 9) * 3 - 12, 376) - ub;
  int aiB = iclip(ri + (cB / 9) * 3 - 12, 376) - bi;
  int ajB = iclip(rj + (cB % 9) * 3 - 12, 376) - ub;
  int roi = ri - bi, roj = rj - ub;
  int r0 = gwave * 4;
  float sccA = 0.f, scrA = 0.f, sccB = 0.f, scrB = 0.f, srr = 0.f;
#pragma unroll
  for (int i = 0; i < 4; i++) {
    int row = r0 + i;
    const float* rr = tileS + (roi + row) * TS + roj;
    const float* ar = tileS + (aiA + row) * TS + ajA;
    const float* br = tileS + (aiB + row) * TS + ajB;
#pragma unroll
    for (int j = 0; j < 8; j++) {
      float rv = rr[j], av = ar[j], bv = br[j];
      sccA += av * av; scrA += av * rv;
      sccB += bv * bv; scrB += bv * rv;
      srr  += rv * rv;
    }
  }
  float dAp = sccA - 2.f * scrA + srr;
  float dBp = sccB - 2.f * scrB + srr;
  wdistP[wv][lane] = dAp;
  if (lane < 17)      wdistP[wv][64 + lane] = dBp;
  else if (lane < 20) wdistP[wv][64 + lane] = gwave ? 0.f : FINF;
  __syncthreads();

  // ---------- rank-count top-16 on summed partials (= lax.top_k order) ----
  // step1: distances are exact integers -> partial sums exact -> selection
  // identical to 8-row serial version. wave0 ranks cands 0-63, wave1 64-80.
  float dme; int idxme, smine;
  if (gwave == 0) {
    dme = wdistP[2 * gl][lane] + wdistP[2 * gl + 1][lane];
    idxme = lane; smine = (aiA << 8) | ajA;
  } else {
    dme = lane < 17 ? (wdistP[2 * gl][64 + lane] + wdistP[2 * gl + 1][64 + lane])
                    : FINF;
    idxme = 64 + lane; smine = (aiB << 8) | ajB;
  }
  {
    int rank = 0;
    const float4* p0 = (const float4*)&wdistP[2 * gl][0];
    const float4* p1 = (const float4*)&wdistP[2 * gl + 1][0];
#pragma unroll 3
    for (int c4 = 0; c4 < 21; c4++) {
      float4 v = p0[c4], u = p1[c4];
      float ev[4] = {v.x + u.x, v.y + u.y, v.z + u.z, v.w + u.w};
#pragma unroll
      for (int j = 0; j < 4; j++) {
        int c2 = c4 * 4 + j;
        rank += (ev[j] < dme || (ev[j] == dme && c2 < idxme)) ? 1 : 0;
      }
    }
    bool dowrite = (gwave == 0) || (lane < 17);
    if (dowrite && rank < 16) wsel[gl][rank] = smine;
  }
  __syncthreads();

  // ---------- per-lane geometry: patch k, row r8 ----------
  int k = (gwave << 3) | (lane >> 3);
  int r8 = lane & 7;
  int sp = wsel[gl][k];
  int gi = (sp >> 8) + r8, gj = sp & 255;

  float Ca[8];                              // D8[r8][b] for col-fwd
  *(float4*)&Ca[0] = *(const float4*)&ldsD[r8 * 8];
  *(float4*)&Ca[4] = *(const float4*)&ldsD[r8 * 8 + 4];

  float4* xs = &xbuf[wv][lane];
  const float4* xp = &xbuf[wv ^ 1][lane];

  float X[8], w;

  if (WIEN) {
    float Z[8];
#pragma unroll
    for (int c = 0; c < 8; c++) Z[c] = tileS[gi * TS + gj + c];
    fwd8(Z, Ca);
    had16x(Z, lane, gwave, xs, xp);          // cb

#pragma unroll
    for (int c = 0; c < 8; c++) X[c] = tileN[gi * TS + gj + c];
    fwd8(X, Ca);
    had16x(X, lane, gwave, xs, xp);          // cn

    float part = 0.f;
#pragma unroll
    for (int d = 0; d < 8; d++) {
      float cb = Z[d];
      float we = cb * cb / (cb * cb + sigma2);
      X[d] = we * X[d];
      part += we * we;
    }
#pragma unroll
    for (int m = 1; m <= 32; m <<= 1) part += sxor_f(part, m);
    if (lane == 0) pbuf[wv] = part;
    __syncthreads();
    float tot = pbuf[2 * gl] + pbuf[2 * gl + 1];
    w = 1.f / (sigma2 * fmaxf(tot, 1e-8f));
  } else {
#pragma unroll
    for (int c = 0; c < 8; c++) X[c] = tileN[gi * TS + gj + c];
    fwd8(X, Ca);
    had16x(X, lane, gwave, xs, xp);

    float thr = 2.7f * sqrtf(sigma2);
    int cnt = 0;
#pragma unroll
    for (int d = 0; d < 8; d++) {
      // DC element (k=0,a=0,d=0) = wave0, lane0, d0
      bool keep = (fabsf(X[d]) > thr) || (gwave == 0 && lane == 0 && d == 0);
      cnt += (int)__popcll(__ballot(keep));
      if (!keep) X[d] = 0.f;
    }
    if (lane == 0) pbuf[wv] = (float)cnt;
    __syncthreads();
    float tot = pbuf[2 * gl] + pbuf[2 * gl + 1];
    w = 1.f / (sigma2 * fmaxf(tot, 1.f));
  }

  // ---------- inverse 3D transform ----------
  had16x(X, lane, gwave, xs, xp);
  float Ct[8];
#pragma unroll
  for (int a = 0; a < 8; a++) Ct[a] = ldsD[a * 8 + r8];   // D^T rows
  inv8(X, Ct);

  // ---------- accumulate (suppressed for the clamped tail group) ----------
  if (active) {
#pragma unroll
    for (int c = 0; c < 8; c++) {
      int off = gi * TS + gj + c;
      atomicAdd(&accN[off], w * X[c]);
      atomicAdd(&accD[off], w);
    }
  }
  __syncthreads();

  for (int e = t; e < 32 * TS; e += 512) {
    float dv = accD[e];
    if (dv != 0.f) {
      int r = e / TS, c = e - r * TS;
      int gp = (bi + r) * 384 + ub + c;
      atomicAdd(&num[gp], accN[e]);
      atomicAdd(&den[gp], dv);
    }
  }
}

__global__ void div_kernel(const float* __restrict__ num,
                           const float* __restrict__ den,
                           float* __restrict__ out, int npix) {
  int i = blockIdx.x * blockDim.x + threadIdx.x;
  if (i < npix) out[i] = num[i] / fmaxf(den[i], 1e-8f);
}

extern "C" void kernel_launch(void* const* d_in, const int* in_sizes, int n_in,
                              void* d_out, int out_size, void* d_ws, size_t ws_size,
                              hipStream_t stream) {
  const int* img  = (const int*)d_in[0];
  const int* pvar = (const int*)d_in[1];
  float* out = (float*)d_out;
  float* ws  = (float*)d_ws;

  float* num1 = ws + 0 * NPIX;
  float* den1 = ws + 1 * NPIX;
  float* num2 = ws + 2 * NPIX;
  float* den2 = ws + 3 * NPIX;

  hipMemsetAsync(num1, 0, (size_t)4 * NPIX * sizeof(float), stream);

  const int NBLK = 95 * 24;   // 95 rows x 24 col-blocks (4 groups each)
  bm3d_pass<0><<<NBLK, 512, 0, stream>>>(img, nullptr, nullptr, pvar, num1, den1);
  bm3d_pass<1><<<NBLK, 512, 0, stream>>>(img, num1, den1, pvar, num2, den2);
  div_kernel<<<(NPIX + 255) / 256, 256, 0, stream>>>(num2, den2, out, NPIX);
}

// Round 19
// 273.159 us; speedup vs baseline: 1.1880x; 1.1880x over previous
//
#include <hip/hip_runtime.h>
#include <math.h>

#define TS 45            // LDS tile stride (32 rows x 44 used cols, +1 pad)
#define FINF 3.4e38f

__device__ __forceinline__ int iclip(int v, int hi) {
  return v < 0 ? 0 : (v > hi ? hi : v);
}

// Exact f32 values of the reference D8 (computed in f64, cast to f32).
constexpr float CA = 0.35355339059327373f;
constexpr float K1 = 0.49039264020161522f;
constexpr float K2 = 0.46193976625564337f;
constexpr float K3 = 0.41573480615127262f;
constexpr float K4 = 0.35355339059327379f;
constexpr float K5 = 0.27778511650980111f;
constexpr float K6 = 0.19134171618254489f;
constexpr float K7 = 0.097545161008064135f;

constexpr float DCT8[8][8] = {
  { CA, CA, CA, CA, CA, CA, CA, CA},
  { K1, K3, K5, K7,-K7,-K5,-K3,-K1},
  { K2, K6,-K6,-K2,-K2,-K6, K6, K2},
  { K3,-K7,-K1,-K5, K5, K1, K7,-K3},
  { K4,-K4,-K4, K4, K4,-K4,-K4, K4},
  { K5,-K1, K7, K3,-K3,-K7, K1,-K5},
  { K6,-K2, K2,-K6,-K6, K2,-K2, K6},
  { K7,-K5, K3,-K1, K1,-K3, K5,-K7},
};

// lane-xor exchange: DPP for 1/2, ds_swizzle for 4/8/16, shfl for 32
__device__ __forceinline__ int sxor_i(int v, int m) {
  switch (m) {
    case 1:  return __builtin_amdgcn_update_dpp(0, v, 0xB1, 0xF, 0xF, true); // quad_perm [1,0,3,2]
    case 2:  return __builtin_amdgcn_update_dpp(0, v, 0x4E, 0xF, 0xF, true); // quad_perm [2,3,0,1]
    case 4:  return __builtin_amdgcn_ds_swizzle(v, (4 << 10) | 0x1F);
    case 8:  return __builtin_amdgcn_ds_swizzle(v, (8 << 10) | 0x1F);
    case 16: return __builtin_amdgcn_ds_swizzle(v, (16 << 10) | 0x1F);
    default: return __shfl_xor(v, 32, 64);
  }
}
__device__ __forceinline__ float sxor_f(float v, int m) {
  return __int_as_float(sxor_i(__float_as_int(v), m));
}

// broadcast from quad lane s (VALU DPP, no LDS pipe)
__device__ __forceinline__ float qbcast(float v, int s) {
  int x = __float_as_int(v), r;
  switch (s) {
    case 0:  r = __builtin_amdgcn_update_dpp(0, x, 0x00, 0xF, 0xF, true); break;
    case 1:  r = __builtin_amdgcn_update_dpp(0, x, 0x55, 0xF, 0xF, true); break;
    case 2:  r = __builtin_amdgcn_update_dpp(0, x, 0xAA, 0xF, 0xF, true); break;
    default: r = __builtin_amdgcn_update_dpp(0, x, 0xFF, 0xF, 0xF, true); break;
  }
  return __int_as_float(r);
}

// forward: row DCT (lane-local, literal coeffs) then column DCT (quad mix)
__device__ __forceinline__ void fwd_rowcol(float X[2][8], float U[2][8],
                                           const float Ca0[8], const float Ca1[8]) {
#pragma unroll
  for (int r = 0; r < 2; r++)
#pragma unroll
    for (int d = 0; d < 8; d++) {
      float s = X[r][0] * DCT8[d][0];
#pragma unroll
      for (int c = 1; c < 8; c++) s += X[r][c] * DCT8[d][c];
      U[r][d] = s;
    }
#pragma unroll
  for (int r = 0; r < 2; r++)
#pragma unroll
    for (int d = 0; d < 8; d++) X[r][d] = 0.f;
#pragma unroll
  for (int b = 0; b < 8; b++)
#pragma unroll
    for (int d = 0; d < 8; d++) {
      float yb = qbcast(U[b & 1][d], b >> 1);
      X[0][d] += Ca0[b] * yb;
      X[1][d] += Ca1[b] * yb;
    }
}

// inverse: column (quad mix, D^T coeffs) then row (lane-local literals)
__device__ __forceinline__ void inv_colrow(float X[2][8], float U[2][8],
                                           const float Ct0[8], const float Ct1[8]) {
#pragma unroll
  for (int r = 0; r < 2; r++)
#pragma unroll
    for (int d = 0; d < 8; d++) U[r][d] = 0.f;
#pragma unroll
  for (int a = 0; a < 8; a++)
#pragma unroll
    for (int d = 0; d < 8; d++) {
      float za = qbcast(X[a & 1][d], a >> 1);
      U[0][d] += Ct0[a] * za;
      U[1][d] += Ct1[a] * za;
    }
#pragma unroll
  for (int r = 0; r < 2; r++)
#pragma unroll
    for (int c = 0; c < 8; c++) {
      float s = U[r][0] * DCT8[0][c];
#pragma unroll
      for (int d = 1; d < 8; d++) s += U[r][d] * DCT8[d][c];
      X[r][c] = s;
    }
}

// 16-point Walsh-Hadamard across lane bits 2..5 (k dim), scale 1/4
__device__ __forceinline__ void had16r(float X[2][8], int lane) {
#pragma unroll
  for (int m = 4; m <= 32; m <<= 1) {
    bool hi = (lane & m) != 0;
#pragma unroll
    for (int r = 0; r < 2; r++)
#pragma unroll
      for (int d = 0; d < 8; d++) {
        float tv = sxor_f(X[r][d], m);
        X[r][d] = hi ? (tv - X[r][d]) : (X[r][d] + tv);
      }
  }
#pragma unroll
  for (int r = 0; r < 2; r++)
#pragma unroll
    for (int d = 0; d < 8; d++) X[r][d] *= 0.25f;
}

template <int WIEN>
__device__ __forceinline__ void group_worker(
    const float* __restrict__ tileS, const float* __restrict__ tileN,
    float* __restrict__ accN, float* __restrict__ accD,
    const float* __restrict__ ldsD, int* __restrict__ sel,
    float* __restrict__ wdrow,
    int lane, int ri, int rj, int bi, int ub, float sigma2) {

  // ---------- block match: 81 candidates, lane holds cand lane and 64+lane ----
  int cB = lane < 17 ? 64 + lane : 80;
  int aiA = iclip(ri + (lane / 9) * 3 - 12, 376) - bi;
  int ajA = iclip(rj + (lane % 9) * 3 - 12, 376) - ub;
  int aiB = iclip(ri + (cB / 9) * 3 - 12, 376) - bi;
  int ajB = iclip(rj + (cB % 9) * 3 - 12, 376) - ub;
  int roi = ri - bi, roj = rj - ub;
  float sccA = 0.f, scrA = 0.f, sccB = 0.f, scrB = 0.f, srr = 0.f;
#pragma unroll
  for (int i = 0; i < 8; i++) {
    const float* rr = tileS + (roi + i) * TS + roj;
    const float* ar = tileS + (aiA + i) * TS + ajA;
    const float* br = tileS + (aiB + i) * TS + ajB;
#pragma unroll
    for (int j = 0; j < 8; j++) {
      float rv = rr[j], av = ar[j], bv = br[j];
      sccA += av * av; scrA += av * rv;
      sccB += bv * bv; scrB += bv * rv;
      srr  += rv * rv;
    }
  }
  float d0 = sccA - 2.f * scrA + srr;
  float d1 = lane < 17 ? (sccB - 2.f * scrB + srr) : FINF;

  // ---------- rank-count top-16 (lexicographic (d, idx) = lax.top_k order) ----
  // per-wave dist table; same-wave LDS RAW (compiler inserts lgkm waits)
  wdrow[lane] = d0;
  if (lane < 17)      wdrow[64 + lane] = d1;
  else if (lane < 20) wdrow[64 + lane] = FINF;

  int rank0 = 0, rank1 = 0;
  const float4* wp = (const float4*)wdrow;
  int idxB = 64 + lane;
#pragma unroll 3
  for (int c4 = 0; c4 < 21; c4++) {
    float4 v = wp[c4];
    float ev[4] = {v.x, v.y, v.z, v.w};
#pragma unroll
    for (int u = 0; u < 4; u++) {
      int c2 = c4 * 4 + u;
      rank0 += (ev[u] < d0 || (ev[u] == d0 && c2 < lane)) ? 1 : 0;
      rank1 += (ev[u] < d1 || (ev[u] == d1 && c2 < idxB)) ? 1 : 0;
    }
  }
  if (rank0 < 16) sel[rank0] = (aiA << 8) | ajA;
  if (lane < 17 && rank1 < 16) sel[rank1] = (aiB << 8) | ajB;

  // ---------- per-lane geometry + column-DCT coefficient rows ---------------
  int q = lane & 3, k = lane >> 2;
  float Ca0[8], Ca1[8];
#pragma unroll
  for (int b = 0; b < 8; b++) {
    Ca0[b] = ldsD[(2 * q) * 8 + b];
    Ca1[b] = ldsD[(2 * q + 1) * 8 + b];
  }
  int sp = sel[k];
  int gi = (sp >> 8) + 2 * q, gj = sp & 255;

  float X[2][8], U[2][8], ZB[2][8];
  float w;

  if (WIEN) {                      // cb = fwd3d(basic group)
#pragma unroll
    for (int r = 0; r < 2; r++)
#pragma unroll
      for (int c = 0; c < 8; c++) ZB[r][c] = tileS[(gi + r) * TS + gj + c];
    fwd_rowcol(ZB, U, Ca0, Ca1);
    had16r(ZB, lane);
  }

  // cn / noisy group
#pragma unroll
  for (int r = 0; r < 2; r++)
#pragma unroll
    for (int c = 0; c < 8; c++) X[r][c] = tileN[(gi + r) * TS + gj + c];
  fwd_rowcol(X, U, Ca0, Ca1);
  had16r(X, lane);

  if (WIEN) {
    float part = 0.f;
#pragma unroll
    for (int r = 0; r < 2; r++)
#pragma unroll
      for (int d = 0; d < 8; d++) {
        float cb = ZB[r][d];
        float we = cb * cb / (cb * cb + sigma2);
        X[r][d] = we * X[r][d];
        part += we * we;
      }
#pragma unroll
    for (int m = 1; m <= 32; m <<= 1) part += sxor_f(part, m);
    w = 1.f / (sigma2 * fmaxf(part, 1e-8f));
  } else {
    float thr = 2.7f * sqrtf(sigma2);
    int cnt = 0;
#pragma unroll
    for (int r = 0; r < 2; r++)
#pragma unroll
      for (int d = 0; d < 8; d++) {
        bool keep = (fabsf(X[r][d]) > thr) || (lane == 0 && r == 0 && d == 0);
        cnt += (int)__popcll(__ballot(keep));
        if (!keep) X[r][d] = 0.f;
      }
    w = 1.f / (sigma2 * fmaxf((float)cnt, 1.f));
  }

  // ---------- inverse 3D transform ------------------------------------------
  had16r(X, lane);
#pragma unroll
  for (int a = 0; a < 8; a++) {    // D^T rows for this lane's two b's
    Ca0[a] = ldsD[a * 8 + 2 * q];
    Ca1[a] = ldsD[a * 8 + 2 * q + 1];
  }
  inv_colrow(X, U, Ca0, Ca1);

  // ---------- accumulate into shared num/den tiles ---------------------------
#pragma unroll
  for (int r = 0; r < 2; r++)
#pragma unroll
    for (int c = 0; c < 8; c++) {
      int off = (gi + r) * TS + gj + c;
      atomicAdd(&accN[off], w * X[r][c]);
      atomicAdd(&accD[off], w);
    }
}

// WIEN=0: match source = img (int). WIEN=1: match source = num1/den1 (basic).
template <int WIEN>
__global__ __launch_bounds__(256, 6) void bm3d_pass(
    const int* __restrict__ img,
    const float* __restrict__ bn, const float* __restrict__ bd,
    const int* __restrict__ pvar,
    float* __restrict__ num, float* __restrict__ den) {
  __shared__ float ldsD[64];
  __shared__ int   ldsSel[4][16];
  __shared__ __align__(16) float wdist[4][84];
  __shared__ float tileN[32 * TS];
  __shared__ float tileB[WIEN ? 32 * TS : 1];
  __shared__ float accN[32 * TS], accD[32 * TS];

  int t = threadIdx.x;
  int brow = blockIdx.x / 24, bcb = blockIdx.x - brow * 24;
  int ri = brow * 4;
  int bim = ri - 12;      int bi = bim < 0 ? 0 : (bim > 352 ? 352 : bim);
  int ubm = 16 * bcb - 12; int ub = ubm < 0 ? 0 : (ubm > 352 ? 352 : ubm);

  if (t < 64) ldsD[t] = DCT8[t >> 3][t & 7];
  for (int e = t; e < 32 * 44; e += 256) {
    int r = e / 44, c = e - r * 44;
    int col = ub + c;
    bool ok = col < 384;
    int gidx = (bi + r) * 384 + col;
    tileN[r * TS + c] = ok ? (float)img[gidx] : 0.f;
    if (WIEN)  // basic = num1 / max(den1, 1e-8), same expr as old div kernel
      tileB[r * TS + c] = ok ? (bn[gidx] / fmaxf(bd[gidx], 1e-8f)) : 0.f;
  }
  for (int e = t; e < 32 * TS; e += 256) { accN[e] = 0.f; accD[e] = 0.f; }
  __syncthreads();

  float sigma2 = (float)pvar[0];
  int wv = t >> 6, lane = t & 63;
  int gc = bcb * 4 + wv;
  if (gc < 95) {
    group_worker<WIEN>(WIEN ? tileB : tileN, tileN, accN, accD, ldsD,
                       &ldsSel[wv][0], &wdist[wv][0],
                       lane, ri, gc * 4, bi, ub, sigma2);
  }
  __syncthreads();

  for (int e = t; e < 32 * TS; e += 256) {
    float dv = accD[e];
    if (dv != 0.f) {
      int r = e / TS, c = e - r * TS;
      int gp = (bi + r) * 384 + ub + c;
      atomicAdd(&num[gp], accN[e]);
      atomicAdd(&den[gp], dv);
    }
  }
}

__global__ void div_kernel(const float* __restrict__ num,
                           const float* __restrict__ den,
                           float* __restrict__ out, int npix) {
  int i = blockIdx.x * blockDim.x + threadIdx.x;
  if (i < npix) out[i] = num[i] / fmaxf(den[i], 1e-8f);
}

extern "C" void kernel_launch(void* const* d_in, const int* in_sizes, int n_in,
                              void* d_out, int out_size, void* d_ws, size_t ws_size,
                              hipStream_t stream) {
  const int* img  = (const int*)d_in[0];
  const int* pvar = (const int*)d_in[1];
  float* out = (float*)d_out;
  float* ws  = (float*)d_ws;

  const int NPIX = 384 * 384;
  float* num1 = ws + 0 * NPIX;
  float* den1 = ws + 1 * NPIX;
  float* num2 = ws + 2 * NPIX;
  float* den2 = ws + 3 * NPIX;

  // single memset over contiguous num1|den1|num2|den2
  hipMemsetAsync(num1, 0, (size_t)4 * NPIX * sizeof(float), stream);

  const int NBLK = 95 * 24;   // 95 rows x 24 col-blocks (4 groups each)
  bm3d_pass<0><<<NBLK, 256, 0, stream>>>(img, nullptr, nullptr, pvar, num1, den1);
  bm3d_pass<1><<<NBLK, 256, 0, stream>>>(img, num1, den1, pvar, num2, den2);
  div_kernel<<<(NPIX + 255) / 256, 256, 0, stream>>>(num2, den2, out, NPIX);
}